// Round 3
// baseline (157.237 us; speedup 1.0000x reference)
//
#include <hip/hip_runtime.h>

#define NH 8
#define LQ 384
#define LK 384
#define BS 2

// ---------------- Kernel 1: Ek = exp(2*(kW+b1)), layout [bh][e][k] ----------------
// grid = 192: bh = bid/12, 32-k tile = bid%12. 1.5MB into ws.
__global__ __launch_bounds__(256) void pre_ek_kernel(
    const float* __restrict__ kin, const float* __restrict__ w1,
    const float* __restrict__ b1, float* __restrict__ ws)
{
    __shared__ float tile[32][65];
    const int bid = blockIdx.x;
    const int bh = bid / 12, kt = bid % 12;
    const int b = bh >> 3, h = bh & 7;
    const int k0 = kt * 32;
    const int lane = threadIdx.x & 63, w = threadIdx.x >> 6;

    float w1c[32];
    const float* w1p = w1 + (size_t)(h * 64 + 32) * 64 + lane;
    #pragma unroll
    for (int d = 0; d < 32; ++d) w1c[d] = w1p[d * 64];
    const float bv = b1[h * 64 + lane];

    #pragma unroll
    for (int s = 0; s < 8; ++s) {
        int kr = w * 8 + s;
        const float* krow = kin + ((size_t)(b * LK + k0 + kr)) * (NH * 32) + h * 32;
        float acc = bv;
        #pragma unroll
        for (int d = 0; d < 32; ++d) acc = __builtin_fmaf(krow[d], w1c[d], acc);
        tile[kr][lane] = __expf(acc + acc);
    }
    __syncthreads();
    float* wk = ws + (size_t)bh * 64 * LK + k0;
    const int k32 = lane & 31, eh = lane >> 5;
    #pragma unroll
    for (int s2 = 0; s2 < 8; ++s2) {
        int e = w * 16 + s2 * 2 + eh;
        wk[(size_t)e * LK + k32] = tile[k32][e];   // 128B segments, coalesced
    }
}

// ---------------- Kernel 2: Eq fused + scores (quad-rcp) + softmax + att + PV ----------------
// grid = 768: bh = blk/48, q-tile of 8; 4 waves, 2 q-rows per wave.
__global__ __launch_bounds__(256, 4) void attn_kernel(
    const float* __restrict__ qin, const float* __restrict__ vin,
    const int* __restrict__ qlens, const int* __restrict__ klens,
    const float* __restrict__ w1, const float* __restrict__ w2g,
    const float* __restrict__ ws,
    float* __restrict__ outg, float* __restrict__ attg)
{
    __shared__ __align__(16) float ek[16 * LK];      // 24KB: Ek chunk, later V half [192][32]
    __shared__ __align__(16) float att_s[8][LK];     // 12KB
    __shared__ __align__(16) float eqs[8 * 64];      // 2KB
    __shared__ __align__(16) float w2s[64];

    const int tid = threadIdx.x, wave = tid >> 6, lane = tid & 63;
    const int bh = blockIdx.x / 48, tile = blockIdx.x % 48;
    const int b = bh >> 3, h = bh & 7;
    const int q0 = tile * 8;
    const int klen = klens[b], qlen = qlens[b];

    if (tid < 16) ((float4*)w2s)[tid] = ((const float4*)(w2g + h * 64))[tid];

    // ---- Eq prologue: rows {wave, wave+4}, e = lane. Zero redundancy. ----
    {
        float w1c[32];
        const float* w1q = w1 + (size_t)(h * 64) * 64 + lane;
        #pragma unroll
        for (int d = 0; d < 32; ++d) w1c[d] = w1q[d * 64];
        const float* qr0 = qin + ((size_t)(b * LQ + q0 + wave)) * (NH * 32) + h * 32;
        const float* qr1 = qr0 + 4 * (NH * 32);
        float a0 = 0.f, a1 = 0.f;
        #pragma unroll
        for (int d = 0; d < 32; ++d) {
            a0 = __builtin_fmaf(qr0[d], w1c[d], a0);
            a1 = __builtin_fmaf(qr1[d], w1c[d], a1);
        }
        eqs[wave * 64 + lane]       = __expf(a0 + a0);
        eqs[(wave + 4) * 64 + lane] = __expf(a1 + a1);
    }

    float sc[2][6];
    #pragma unroll
    for (int i = 0; i < 2; ++i)
        #pragma unroll
        for (int j = 0; j < 6; ++j) sc[i][j] = 0.f;

    const float* ekg = ws + (size_t)bh * 64 * LK;
    const float4* eq0p = (const float4*)(eqs + (wave * 2 + 0) * 64);
    const float4* eq1p = (const float4*)(eqs + (wave * 2 + 1) * 64);

    for (int ec = 0; ec < 4; ++ec) {
        __syncthreads();   // (1st iter: also covers eqs/w2s writes)
        const float4* src = (const float4*)(ekg + (size_t)ec * 16 * LK);
        #pragma unroll
        for (int r = 0; r < 6; ++r)
            ((float4*)ek)[tid + r * 256] = src[tid + r * 256];
        __syncthreads();
        #pragma unroll
        for (int q4 = 0; q4 < 4; ++q4) {
            float4 wv  = ((const float4*)w2s)[ec * 4 + q4];
            float4 eqv0 = eq0p[ec * 4 + q4];
            float4 eqv1 = eq1p[ec * 4 + q4];
            const float* ekb = ek + (q4 * 4) * LK + lane;
            #pragma unroll
            for (int j = 0; j < 6; ++j) {
                float kv0 = ekb[j * 64];
                float kv1 = ekb[LK + j * 64];
                float kv2 = ekb[2 * LK + j * 64];
                float kv3 = ekb[3 * LK + j * 64];
                {   // row 0:  sum_u w_u/(1+Eq_u*Ek_u) with one rcp
                    float t0 = __builtin_fmaf(eqv0.x, kv0, 1.f);
                    float t1 = __builtin_fmaf(eqv0.y, kv1, 1.f);
                    float t2 = __builtin_fmaf(eqv0.z, kv2, 1.f);
                    float t3 = __builtin_fmaf(eqv0.w, kv3, 1.f);
                    float p12 = t0 * t1, p34 = t2 * t3;
                    float n12 = wv.x * t1; n12 = __builtin_fmaf(wv.y, t0, n12);
                    float n34 = wv.z * t3; n34 = __builtin_fmaf(wv.w, t2, n34);
                    float num = n12 * p34; num = __builtin_fmaf(n34, p12, num);
                    sc[0][j] = __builtin_fmaf(num, __builtin_amdgcn_rcpf(p12 * p34), sc[0][j]);
                }
                {   // row 1
                    float t0 = __builtin_fmaf(eqv1.x, kv0, 1.f);
                    float t1 = __builtin_fmaf(eqv1.y, kv1, 1.f);
                    float t2 = __builtin_fmaf(eqv1.z, kv2, 1.f);
                    float t3 = __builtin_fmaf(eqv1.w, kv3, 1.f);
                    float p12 = t0 * t1, p34 = t2 * t3;
                    float n12 = wv.x * t1; n12 = __builtin_fmaf(wv.y, t0, n12);
                    float n34 = wv.z * t3; n34 = __builtin_fmaf(wv.w, t2, n34);
                    float num = n12 * p34; num = __builtin_fmaf(n34, p12, num);
                    sc[1][j] = __builtin_fmaf(num, __builtin_amdgcn_rcpf(p12 * p34), sc[1][j]);
                }
            }
        }
    }

    // ---- softmax over k (score = -2*acc; Sum(w2) shift dropped) ----
    #pragma unroll
    for (int i = 0; i < 2; ++i) {
        int row = wave * 2 + i, q = q0 + row;
        float s_[6], p[6];
        float m = -3.4e38f;
        #pragma unroll
        for (int j = 0; j < 6; ++j) {
            int kk = j * 64 + lane;
            float v = -2.0f * sc[i][j];
            s_[j] = (kk < klen) ? v : -3.4e38f;
            m = fmaxf(m, s_[j]);
        }
        #pragma unroll
        for (int off = 32; off >= 1; off >>= 1) m = fmaxf(m, __shfl_xor(m, off));
        float ssum = 0.f;
        #pragma unroll
        for (int j = 0; j < 6; ++j) {
            int kk = j * 64 + lane;
            p[j] = (kk < klen) ? __expf(s_[j] - m) : 0.f;
            ssum += p[j];
        }
        #pragma unroll
        for (int off = 32; off >= 1; off >>= 1) ssum += __shfl_xor(ssum, off);
        float inv = __builtin_amdgcn_rcpf(ssum);
        float* arow = att_s[row];
        float* ag = attg + ((size_t)(bh * LQ + q)) * LK;
        #pragma unroll
        for (int j = 0; j < 6; ++j) {
            float a = p[j] * inv;
            arow[j * 64 + lane] = a;
            ag[j * 64 + lane]   = a;
        }
    }

    // ---- PV: lane = kf*8+dg; V half staged in ek arena; b128 V reads shared by 2 rows ----
    const int kf = lane >> 3, dg = lane & 7;
    float oa[2][4] = {{0.f,0.f,0.f,0.f},{0.f,0.f,0.f,0.f}};
    const float* ar0 = att_s[wave * 2 + 0];
    const float* ar1 = att_s[wave * 2 + 1];
    for (int c = 0; c < 2; ++c) {
        __syncthreads();   // all waves done with ek (score / prior V half)
        const float4* vg = (const float4*)(vin + ((size_t)(b * LK + c * 192)) * (NH * 32) + h * 32);
        #pragma unroll
        for (int r = 0; r < 6; ++r) {
            int fidx = tid + r * 256;
            int kk = fidx >> 3, d4 = fidx & 7;
            ((float4*)ek)[fidx] = vg[(size_t)kk * 64 + d4];
        }
        __syncthreads();
        const float* a0p = ar0 + c * 192;
        const float* a1p = ar1 + c * 192;
        #pragma unroll 6
        for (int k0 = 0; k0 < 192; k0 += 8) {
            float4 vv = ((const float4*)ek)[(k0 + kf) * 8 + dg];
            float a0 = a0p[k0 + kf];
            float a1 = a1p[k0 + kf];
            oa[0][0] = __builtin_fmaf(a0, vv.x, oa[0][0]);
            oa[0][1] = __builtin_fmaf(a0, vv.y, oa[0][1]);
            oa[0][2] = __builtin_fmaf(a0, vv.z, oa[0][2]);
            oa[0][3] = __builtin_fmaf(a0, vv.w, oa[0][3]);
            oa[1][0] = __builtin_fmaf(a1, vv.x, oa[1][0]);
            oa[1][1] = __builtin_fmaf(a1, vv.y, oa[1][1]);
            oa[1][2] = __builtin_fmaf(a1, vv.z, oa[1][2]);
            oa[1][3] = __builtin_fmaf(a1, vv.w, oa[1][3]);
        }
    }
    #pragma unroll
    for (int i = 0; i < 2; ++i)
        #pragma unroll
        for (int u = 0; u < 4; ++u) {
            float x = oa[i][u];
            x += __shfl_xor(x, 8);
            x += __shfl_xor(x, 16);
            x += __shfl_xor(x, 32);
            oa[i][u] = x;
        }
    if (kf == 0) {   // lanes 0..7, dg = lane
        #pragma unroll
        for (int i = 0; i < 2; ++i) {
            int q = q0 + wave * 2 + i;
            float4 o4;
            o4.x = (q < qlen) ? oa[i][0] : 0.f;
            o4.y = (q < qlen) ? oa[i][1] : 0.f;
            o4.z = (q < qlen) ? oa[i][2] : 0.f;
            o4.w = (q < qlen) ? oa[i][3] : 0.f;
            ((float4*)(outg + ((size_t)(b * LQ + q)) * (NH * 32) + h * 32))[dg] = o4;
        }
    }
}

extern "C" void kernel_launch(void* const* d_in, const int* in_sizes, int n_in,
                              void* d_out, int out_size, void* d_ws, size_t ws_size,
                              hipStream_t stream) {
    const float* q    = (const float*)d_in[0];
    const float* k    = (const float*)d_in[1];
    const float* v    = (const float*)d_in[2];
    const int*   qlen = (const int*)d_in[3];
    const int*   klen = (const int*)d_in[4];
    const float* w1   = (const float*)d_in[5];
    const float* b1   = (const float*)d_in[6];
    const float* w2   = (const float*)d_in[7];
    float* out = (float*)d_out;
    float* att = out + (size_t)BS * LQ * NH * 32;   // out: 196608, att: 2359296 floats
    float* ws  = (float*)d_ws;                      // Ek only: 393216 floats = 1.5 MB

    pre_ek_kernel<<<192, 256, 0, stream>>>(k, w1, b1, ws);
    attn_kernel<<<768, 256, 0, stream>>>(q, v, qlen, klen, w1, w2, ws, out, att);
}

// Round 4
// 111.037 us; speedup vs baseline: 1.4161x; 1.4161x over previous
//
#include <hip/hip_runtime.h>

#define NH 8
#define LQ 384
#define LK 384
#define BS 2

// ---------------- Kernel 1: Ek = exp(2*(kW+b1)), layout [bh][e][k] ----------------
// grid = 192: bh = bid/12, 32-k tile = bid%12. 1.5MB into ws.
__global__ __launch_bounds__(256) void pre_ek_kernel(
    const float* __restrict__ kin, const float* __restrict__ w1,
    const float* __restrict__ b1, float* __restrict__ ws)
{
    __shared__ float tile[32][65];
    const int bid = blockIdx.x;
    const int bh = bid / 12, kt = bid % 12;
    const int b = bh >> 3, h = bh & 7;
    const int k0 = kt * 32;
    const int lane = threadIdx.x & 63, w = threadIdx.x >> 6;

    float w1c[32];
    const float* w1p = w1 + (size_t)(h * 64 + 32) * 64 + lane;
    #pragma unroll
    for (int d = 0; d < 32; ++d) w1c[d] = w1p[d * 64];
    const float bv = b1[h * 64 + lane];

    #pragma unroll
    for (int s = 0; s < 8; ++s) {
        int kr = w * 8 + s;
        const float* krow = kin + ((size_t)(b * LK + k0 + kr)) * (NH * 32) + h * 32;
        float acc = bv;
        #pragma unroll
        for (int d = 0; d < 32; ++d) acc = __builtin_fmaf(krow[d], w1c[d], acc);
        tile[kr][lane] = __expf(acc + acc);
    }
    __syncthreads();
    float* wk = ws + (size_t)bh * 64 * LK + k0;
    const int k32 = lane & 31, eh = lane >> 5;
    #pragma unroll
    for (int s2 = 0; s2 < 8; ++s2) {
        int e = w * 16 + s2 * 2 + eh;
        wk[(size_t)e * LK + k32] = tile[k32][e];   // 128B segments, coalesced
    }
}

// ---------------- Kernel 2: Eq (LDS-staged) + scores (quad-rcp) + softmax + att + PV ----------------
// grid = 768: bh = blk/48, q-tile of 8; 4 waves, 2 q-rows per wave.
__global__ __launch_bounds__(256) void attn_kernel(
    const float* __restrict__ qin, const float* __restrict__ vin,
    const int* __restrict__ qlens, const int* __restrict__ klens,
    const float* __restrict__ w1, const float* __restrict__ w2g,
    const float* __restrict__ ws,
    float* __restrict__ outg, float* __restrict__ attg)
{
    __shared__ __align__(16) float ek[16 * LK];      // 24KB: w1 q-slice, Ek chunks, V halves
    __shared__ __align__(16) float att_s[8][LK];     // 12KB (front 256 floats: q-tile staging)
    __shared__ __align__(16) float eqs[8 * 64];      // 2KB
    __shared__ __align__(16) float w2s[64];

    const int tid = threadIdx.x, wave = tid >> 6, lane = tid & 63;
    const int bh = blockIdx.x / 48, tile = blockIdx.x % 48;
    const int b = bh >> 3, h = bh & 7;
    const int q0 = tile * 8;
    const int klen = klens[b], qlen = qlens[b];

    // ---- stage w1 q-slice (32x64 = 8KB) into ek, q-tile (8x32) into att_s, w2 ----
    {
        const float4* w1g = (const float4*)(w1 + (size_t)h * 64 * 64);  // rows d=0..31 = 512 f4
        ((float4*)ek)[tid]       = w1g[tid];
        ((float4*)ek)[tid + 256] = w1g[tid + 256];
        if (tid < 64) {
            int r = tid >> 3, c = tid & 7;
            ((float4*)att_s)[tid] =
                ((const float4*)(qin + ((size_t)(b * LQ + q0 + r)) * (NH * 32) + h * 32))[c];
        } else if (tid < 80) {
            ((float4*)w2s)[tid - 64] = ((const float4*)(w2g + h * 64))[tid - 64];
        }
    }
    __syncthreads();

    // ---- Eq: rows {wave, wave+4}, e = lane; all operands from LDS ----
    {
        const float* qa = (const float*)att_s;
        float a0 = 0.f, a1 = 0.f;
        #pragma unroll
        for (int d = 0; d < 32; ++d) {
            float wv = ek[d * 64 + lane];            // conflict-free
            a0 = __builtin_fmaf(qa[wave * 32 + d],       wv, a0);   // broadcast
            a1 = __builtin_fmaf(qa[(wave + 4) * 32 + d], wv, a1);
        }
        eqs[wave * 64 + lane]       = __expf(a0 + a0);
        eqs[(wave + 4) * 64 + lane] = __expf(a1 + a1);
    }

    float sc[2][6];
    #pragma unroll
    for (int i = 0; i < 2; ++i)
        #pragma unroll
        for (int j = 0; j < 6; ++j) sc[i][j] = 0.f;

    const float* ekg = ws + (size_t)bh * 64 * LK;
    const float4* eq0p = (const float4*)(eqs + (wave * 2 + 0) * 64);
    const float4* eq1p = (const float4*)(eqs + (wave * 2 + 1) * 64);

    for (int ec = 0; ec < 4; ++ec) {
        __syncthreads();   // 1st iter: also fences Eq-compute reads of ek before overwrite
        const float4* src = (const float4*)(ekg + (size_t)ec * 16 * LK);
        #pragma unroll
        for (int r = 0; r < 6; ++r)
            ((float4*)ek)[tid + r * 256] = src[tid + r * 256];
        __syncthreads();
        #pragma unroll
        for (int q4 = 0; q4 < 4; ++q4) {
            float4 wv   = ((const float4*)w2s)[ec * 4 + q4];
            float4 eqv0 = eq0p[ec * 4 + q4];
            float4 eqv1 = eq1p[ec * 4 + q4];
            const float* ekb = ek + (q4 * 4) * LK + lane;
            #pragma unroll
            for (int j = 0; j < 6; ++j) {
                float kv0 = ekb[j * 64];
                float kv1 = ekb[LK + j * 64];
                float kv2 = ekb[2 * LK + j * 64];
                float kv3 = ekb[3 * LK + j * 64];
                {   // row 0: sum_u w_u/(1+Eq_u*Ek_u) with one rcp per 4 terms
                    float t0 = __builtin_fmaf(eqv0.x, kv0, 1.f);
                    float t1 = __builtin_fmaf(eqv0.y, kv1, 1.f);
                    float t2 = __builtin_fmaf(eqv0.z, kv2, 1.f);
                    float t3 = __builtin_fmaf(eqv0.w, kv3, 1.f);
                    float p12 = t0 * t1, p34 = t2 * t3;
                    float n12 = wv.x * t1; n12 = __builtin_fmaf(wv.y, t0, n12);
                    float n34 = wv.z * t3; n34 = __builtin_fmaf(wv.w, t2, n34);
                    float num = n12 * p34; num = __builtin_fmaf(n34, p12, num);
                    sc[0][j] = __builtin_fmaf(num, __builtin_amdgcn_rcpf(p12 * p34), sc[0][j]);
                }
                {   // row 1
                    float t0 = __builtin_fmaf(eqv1.x, kv0, 1.f);
                    float t1 = __builtin_fmaf(eqv1.y, kv1, 1.f);
                    float t2 = __builtin_fmaf(eqv1.z, kv2, 1.f);
                    float t3 = __builtin_fmaf(eqv1.w, kv3, 1.f);
                    float p12 = t0 * t1, p34 = t2 * t3;
                    float n12 = wv.x * t1; n12 = __builtin_fmaf(wv.y, t0, n12);
                    float n34 = wv.z * t3; n34 = __builtin_fmaf(wv.w, t2, n34);
                    float num = n12 * p34; num = __builtin_fmaf(n34, p12, num);
                    sc[1][j] = __builtin_fmaf(num, __builtin_amdgcn_rcpf(p12 * p34), sc[1][j]);
                }
            }
        }
    }

    // ---- softmax over k (score = -2*acc; Sum(w2) shift dropped) ----
    #pragma unroll
    for (int i = 0; i < 2; ++i) {
        int row = wave * 2 + i, q = q0 + row;
        float s_[6], p[6];
        float m = -3.4e38f;
        #pragma unroll
        for (int j = 0; j < 6; ++j) {
            int kk = j * 64 + lane;
            float v = -2.0f * sc[i][j];
            s_[j] = (kk < klen) ? v : -3.4e38f;
            m = fmaxf(m, s_[j]);
        }
        #pragma unroll
        for (int off = 32; off >= 1; off >>= 1) m = fmaxf(m, __shfl_xor(m, off));
        float ssum = 0.f;
        #pragma unroll
        for (int j = 0; j < 6; ++j) {
            int kk = j * 64 + lane;
            p[j] = (kk < klen) ? __expf(s_[j] - m) : 0.f;
            ssum += p[j];
        }
        #pragma unroll
        for (int off = 32; off >= 1; off >>= 1) ssum += __shfl_xor(ssum, off);
        float inv = __builtin_amdgcn_rcpf(ssum);
        float* arow = att_s[row];
        float* ag = attg + ((size_t)(bh * LQ + q)) * LK;
        #pragma unroll
        for (int j = 0; j < 6; ++j) {
            float a = p[j] * inv;
            arow[j * 64 + lane] = a;
            ag[j * 64 + lane]   = a;
        }
    }

    // ---- PV: lane = kf*8+dg; V half staged in ek arena; b128 V reads shared by 2 rows ----
    const int kf = lane >> 3, dg = lane & 7;
    float oa[2][4] = {{0.f,0.f,0.f,0.f},{0.f,0.f,0.f,0.f}};
    const float* ar0 = att_s[wave * 2 + 0];
    const float* ar1 = att_s[wave * 2 + 1];
    for (int c = 0; c < 2; ++c) {
        __syncthreads();   // all waves done with ek (score / prior V half)
        const float4* vg = (const float4*)(vin + ((size_t)(b * LK + c * 192)) * (NH * 32) + h * 32);
        #pragma unroll
        for (int r = 0; r < 6; ++r) {
            int fidx = tid + r * 256;
            int kk = fidx >> 3, d4 = fidx & 7;
            ((float4*)ek)[fidx] = vg[(size_t)kk * 64 + d4];
        }
        __syncthreads();
        const float* a0p = ar0 + c * 192;
        const float* a1p = ar1 + c * 192;
        #pragma unroll 6
        for (int k0 = 0; k0 < 192; k0 += 8) {
            float4 vv = ((const float4*)ek)[(k0 + kf) * 8 + dg];
            float a0 = a0p[k0 + kf];
            float a1 = a1p[k0 + kf];
            oa[0][0] = __builtin_fmaf(a0, vv.x, oa[0][0]);
            oa[0][1] = __builtin_fmaf(a0, vv.y, oa[0][1]);
            oa[0][2] = __builtin_fmaf(a0, vv.z, oa[0][2]);
            oa[0][3] = __builtin_fmaf(a0, vv.w, oa[0][3]);
            oa[1][0] = __builtin_fmaf(a1, vv.x, oa[1][0]);
            oa[1][1] = __builtin_fmaf(a1, vv.y, oa[1][1]);
            oa[1][2] = __builtin_fmaf(a1, vv.z, oa[1][2]);
            oa[1][3] = __builtin_fmaf(a1, vv.w, oa[1][3]);
        }
    }
    #pragma unroll
    for (int i = 0; i < 2; ++i)
        #pragma unroll
        for (int u = 0; u < 4; ++u) {
            float x = oa[i][u];
            x += __shfl_xor(x, 8);
            x += __shfl_xor(x, 16);
            x += __shfl_xor(x, 32);
            oa[i][u] = x;
        }
    if (kf == 0) {   // lanes 0..7, dg = lane
        #pragma unroll
        for (int i = 0; i < 2; ++i) {
            int q = q0 + wave * 2 + i;
            float4 o4;
            o4.x = (q < qlen) ? oa[i][0] : 0.f;
            o4.y = (q < qlen) ? oa[i][1] : 0.f;
            o4.z = (q < qlen) ? oa[i][2] : 0.f;
            o4.w = (q < qlen) ? oa[i][3] : 0.f;
            ((float4*)(outg + ((size_t)(b * LQ + q)) * (NH * 32) + h * 32))[dg] = o4;
        }
    }
}

extern "C" void kernel_launch(void* const* d_in, const int* in_sizes, int n_in,
                              void* d_out, int out_size, void* d_ws, size_t ws_size,
                              hipStream_t stream) {
    const float* q    = (const float*)d_in[0];
    const float* k    = (const float*)d_in[1];
    const float* v    = (const float*)d_in[2];
    const int*   qlen = (const int*)d_in[3];
    const int*   klen = (const int*)d_in[4];
    const float* w1   = (const float*)d_in[5];
    const float* b1   = (const float*)d_in[6];
    const float* w2   = (const float*)d_in[7];
    float* out = (float*)d_out;
    float* att = out + (size_t)BS * LQ * NH * 32;   // out: 196608, att: 2359296 floats
    float* ws  = (float*)d_ws;                      // Ek only: 393216 floats = 1.5 MB

    pre_ek_kernel<<<192, 256, 0, stream>>>(k, w1, b1, ws);
    attn_kernel<<<768, 256, 0, stream>>>(q, v, qlen, klen, w1, w2, ws, out, att);
}